// Round 21
// baseline (131.421 us; speedup 1.0000x reference)
//
#include <hip/hip_runtime.h>
#include <stdint.h>

#define N_ 4096
#define B_ 1024
#define ROWB 512        // nibble-packed spike row bytes (1024 batches x 4 bits)
#define NSTEPS_ 10
#define DEG_SLOTS 40    // padded neighbor-list slots (deg ~ Poisson(12); P(>40) ~ 1e-11)
#define PAD_E ((uint32_t)(N_ * ROWB)) // sentinel -> byte offset of zero pad row
#define NBLK 256
#define NCTR 16
#define FLAGI 512

// ws layout (bytes):
//   bar  : 0      .. 4224     u32[1056]: 16 ctrs at stride 32 + flag at [512]
//   sExp : 8192   .. ~4.2MB   u4[2][(N+1)*ROWB] spike NIBBLES [n][b]; row N_ always zero
#define OFF_BAR  0
#define OFF_SEXP 8192
#define SEXP_BUF ((N_ + 1) * ROWB)

// zero barrier state each call (graph replays reuse ws; counters are monotonic
// within one call only). Separate dispatch: in-kernel zeroing races arrivals.
__global__ void initbar_k(uint32_t* __restrict__ bar) {
    for (int i = threadIdx.x; i < 1056; i += 256) bar[i] = 0u;
}

// Two-hop grid barrier (round-16/20 champion scheme, verbatim): RELAXED
// L3-homed atomics for arrivals + flag; exactly ONE acquire load (buffer_inv)
// per block per phase, after the flag is seen.
__device__ __forceinline__ void gbar(uint32_t* bar, uint32_t phase) {
    __syncthreads();                         // all waves' spike stores acked
    int tid = threadIdx.x, bid = blockIdx.x;
    if (tid == 0)
        __hip_atomic_fetch_add(&bar[(bid & (NCTR - 1)) * 32], 1u,
                               __ATOMIC_RELAXED, __HIP_MEMORY_SCOPE_AGENT);
    if (bid == 0) {
        if (tid < NCTR) {
            uint32_t tgt = (NBLK / NCTR) * phase;
            while (__hip_atomic_load(&bar[tid * 32], __ATOMIC_RELAXED,
                                     __HIP_MEMORY_SCOPE_AGENT) < tgt)
                __builtin_amdgcn_s_sleep(2);
        }
        __syncthreads();
        if (tid == 0)
            __hip_atomic_store(&bar[FLAGI], phase,
                               __ATOMIC_RELAXED, __HIP_MEMORY_SCOPE_AGENT);
    }
    if (tid == 0) {
        while (__hip_atomic_load(&bar[FLAGI], __ATOMIC_RELAXED,
                                 __HIP_MEMORY_SCOPE_AGENT) < phase)
            __builtin_amdgcn_s_sleep(2);
        (void)__hip_atomic_load(&bar[FLAGI], __ATOMIC_ACQUIRE,  // one buffer_inv
                                __HIP_MEMORY_SCOPE_AGENT);
    }
    __syncthreads();
}

// Persistent kernel (round-20 structure + in-kernel build + byte-packed
// extraction): block = 16 neurons x ALL 1024 batches (1024 threads, 16 waves);
// grid 256 = 1 block/CU. Wave = 1 neuron; refractory wave-local (one
// __ballot/step). Phase A: each wave scans its own C row (4x4 statically
// unrolled float4 loads for MLP) straight into LDS s_nbr. Thread = 1 neuron x
// 16 batches; v in 16 VGPRs all 10 steps. Gather: one uint2 wave-inst reads a
// full 512 B nibble row; accumulate nibble-packed in chunks of <=15 neighbors;
// extraction via even/odd nibble split -> byte-packed sums -> cvt_f32_ubyte.
// Spike nibbles via one relaxed agent-scope b64 atomic store (L3
// write-through); gathers PLAIN loads freshened by the barrier's inv.
__global__ __launch_bounds__(1024, 4) void persist_k(const float* __restrict__ ext,
                                                     const float* __restrict__ C,
                                                     const float* __restrict__ memb,
                                                     const float* __restrict__ thr,
                                                     const float* __restrict__ refr_in,
                                                     unsigned char* __restrict__ sExp,
                                                     float* __restrict__ out,
                                                     uint32_t* bar) {
    __shared__ uint32_t s_nbr[16 * DEG_SLOTS];
    __shared__ uint32_t s_cnt[16];
    __shared__ unsigned char bt[16][528];    // output nibble tile (512 B rows + pad)

    int bid = blockIdx.x;
    int n0 = bid * 16;
    int tid = threadIdx.x;
    int wv = tid >> 6, lane = tid & 63;      // wave wv <-> neuron n0+wv
    int n = n0 + wv;
    int bbatch = lane * 16;                  // first of this thread's 16 batches
    int bbn = lane * 8;                      // nibble byte offset within row

    // ---- phase A: build neighbor list for row n directly into LDS ----
    if (tid < 16) s_cnt[tid] = 0u;
    __syncthreads();
    {
        const float4* row = (const float4*)(C + (size_t)n * N_);
        #pragma unroll
        for (int c = 0; c < 4; ++c) {        // 4 chunks of 4 in-flight float4 loads
            float4 d[4];
            #pragma unroll
            for (int u = 0; u < 4; ++u)
                d[u] = row[lane + (c * 4 + u) * 64];
            #pragma unroll
            for (int u = 0; u < 4; ++u) {
                int base = (lane + (c * 4 + u) * 64) * 4;
                #pragma unroll
                for (int q = 0; q < 4; ++q) {
                    float f = (q == 0) ? d[u].x : (q == 1) ? d[u].y
                            : (q == 2) ? d[u].z : d[u].w;
                    if (f != 0.0f) {
                        uint32_t p = atomicAdd(&s_cnt[wv], 1u);
                        if (p < DEG_SLOTS)
                            s_nbr[wv * DEG_SLOTS + p] = (uint32_t)(base + q) * ROWB;
                    }
                }
            }
        }
    }
    // zero sExp pad rows write-through (first consumed at step-1 gathers,
    // i.e. after gbar(1) -> visible by then)
    if (bid == 1 && tid < 64) {
        __hip_atomic_store((unsigned long long*)(sExp + (size_t)N_ * ROWB) + tid, 0ull,
                           __ATOMIC_RELAXED, __HIP_MEMORY_SCOPE_AGENT);
    } else if (bid == 2 && tid < 64) {
        __hip_atomic_store((unsigned long long*)(sExp + (size_t)SEXP_BUF + (size_t)N_ * ROWB) + tid,
                           0ull, __ATOMIC_RELAXED, __HIP_MEMORY_SCOPE_AGENT);
    }
    __syncthreads();
    for (int i = tid; i < 16 * DEG_SLOTS; i += 1024) {   // sentinel fill
        int rw = i / DEG_SLOTS, sl = i - rw * DEG_SLOTS;
        if ((uint32_t)sl >= min(s_cnt[rw], (uint32_t)DEG_SLOTS)) s_nbr[i] = PAD_E;
    }
    __syncthreads();

    float tn = thr[n];                       // wave-uniform
    float r  = refr_in[n];                   // wave-local refractory state
    uint32_t dg = __builtin_amdgcn_readfirstlane(min(s_cnt[wv], (uint32_t)DEG_SLOTS));
    const uint32_t* lst = &s_nbr[wv * DEG_SLOTS];

    float v[16];
    {
        float mb = memb[n];
        #pragma unroll
        for (int i = 0; i < 16; ++i)         // column loads; lines shared across waves
            v[i] = __fadd_rn(mb, ext[(size_t)(bbatch + i) * N_ + n]);
    }

    uint32_t nib0 = 0, nib1 = 0;             // current step's spikes, nibble-packed

    // ---- step 0: external input only ----
    {
        uint32_t nb = (r != 0.0f) ? 0u : 1u;
        #pragma unroll
        for (int i = 0; i < 16; ++i) {
            int sp = (v[i] > tn) && nb;
            if (i < 8) nib0 |= (uint32_t)sp << (4 * i);
            else       nib1 |= (uint32_t)sp << (4 * (i - 8));
            v[i] = __fmul_rn(sp ? 0.0f : v[i], 0.95f);
        }
        unsigned long long p0 = (unsigned long long)nib0 | ((unsigned long long)nib1 << 32);
        __hip_atomic_store((unsigned long long*)(sExp + (size_t)n * ROWB + bbn), p0,
                           __ATOMIC_RELAXED, __HIP_MEMORY_SCOPE_AGENT);
        int any = (__ballot((nib0 | nib1) != 0) != 0ull);  // any over ALL batches
        r = any ? 3.0f : r;
        r = fminf(fmaxf(__fadd_rn(r, -1.0f), 0.0f), 10.0f);
    }
    gbar(bar, 1);

    // ---- steps 1..9 ----
    unsigned char* sprev = sExp;
    unsigned char* snext = sExp + (size_t)SEXP_BUF;
    for (int s = 1; s < NSTEPS_; ++s) {
        uint32_t nb = (r != 0.0f) ? 0u : 1u;
        uint2 accA = make_uint2(0u, 0u), accB = make_uint2(0u, 0u);
        uint2 accC = make_uint2(0u, 0u), accD = make_uint2(0u, 0u);
        #pragma unroll
        for (int j = 0; j < 8; ++j) {        // chunk A: slots 0..7 (max nibble 8)
            uint32_t e = lst[j];
            uint2 d2 = *(const uint2*)(sprev + e + bbn);
            accA.x += d2.x; accA.y += d2.y;
        }
        #pragma unroll
        for (int j = 8; j < 16; ++j) {       // chunk B: slots 8..15
            uint32_t e = lst[j];
            uint2 d2 = *(const uint2*)(sprev + e + bbn);
            accB.x += d2.x; accB.y += d2.y;
        }
        if (dg > 16) {                       // chunk C: slots 16..30 (15, wave-uniform rare)
            #pragma unroll
            for (int j = 16; j < 31; ++j) {
                uint32_t e = lst[j];
                uint2 d2 = *(const uint2*)(sprev + e + bbn);
                accC.x += d2.x; accC.y += d2.y;
            }
        }
        if (dg > 31) {                       // chunk D: slots 31..39 (9)
            #pragma unroll
            for (int j = 31; j < 40; ++j) {
                uint32_t e = lst[j];
                uint2 d2 = *(const uint2*)(sprev + e + bbn);
                accD.x += d2.x; accD.y += d2.y;
            }
        }
        uint32_t newn0 = 0, newn1 = 0;
        #pragma unroll
        for (int h = 0; h < 2; ++h) {        // dword half: batches 8h..8h+7
            uint32_t a = h ? accA.y : accA.x;
            uint32_t b = h ? accB.y : accB.x;
            uint32_t c = h ? accC.y : accC.x;
            uint32_t d = h ? accD.y : accD.x;
            // even/odd nibble split -> byte-packed sums (each byte <= 40)
            uint32_t sumE = (a & 0x0F0F0F0Fu) + (b & 0x0F0F0F0Fu) +
                            (c & 0x0F0F0F0Fu) + (d & 0x0F0F0F0Fu);   // batches h*8+{0,2,4,6}
            uint32_t sumO = ((a >> 4) & 0x0F0F0F0Fu) + ((b >> 4) & 0x0F0F0F0Fu) +
                            ((c >> 4) & 0x0F0F0F0Fu) + ((d >> 4) & 0x0F0F0F0Fu); // {1,3,5,7}
            uint32_t nh = 0;
            #pragma unroll
            for (int k = 0; k < 4; ++k) {
                float ce = (float)((sumE >> (8 * k)) & 255u);   // cvt_f32_ubyte idiom
                float co = (float)((sumO >> (8 * k)) & 255u);
                int be = h * 8 + 2 * k, bo = be + 1;
                float ve = __fadd_rn(v[be], __fmul_rn(0.1f, ce));
                float vo = __fadd_rn(v[bo], __fmul_rn(0.1f, co));
                int se = (ve > tn) && nb;
                int so = (vo > tn) && nb;
                nh |= (uint32_t)se << (4 * (2 * k));
                nh |= (uint32_t)so << (4 * (2 * k + 1));
                if (s < NSTEPS_ - 1) {
                    v[be] = __fmul_rn(se ? 0.0f : ve, 0.95f);
                    v[bo] = __fmul_rn(so ? 0.0f : vo, 0.95f);
                }
            }
            if (h == 0) newn0 = nh; else newn1 = nh;
        }
        nib0 = newn0; nib1 = newn1;
        if (s < NSTEPS_ - 1) {
            unsigned long long p0 = (unsigned long long)nib0 | ((unsigned long long)nib1 << 32);
            __hip_atomic_store((unsigned long long*)(snext + (size_t)n * ROWB + bbn), p0,
                               __ATOMIC_RELAXED, __HIP_MEMORY_SCOPE_AGENT);
            int any = (__ballot((nib0 | nib1) != 0) != 0ull);
            r = any ? 3.0f : r;
            r = fminf(fmaxf(__fadd_rn(r, -1.0f), 0.0f), 10.0f);
            gbar(bar, (uint32_t)s + 1);
        }
        unsigned char* t = sprev; sprev = snext; snext = t;
    }

    // ---- output: step-9 spike nibbles (in regs) -> tile -> [b][n] float4 ----
    *(uint2*)&bt[wv][bbn] = make_uint2(nib0, nib1);
    __syncthreads();
    #pragma unroll
    for (int p = 0; p < 4; ++p) {
        int i = tid + p * 1024;              // 4096 float4s: 1024 rows x 4 cols
        int rrow = i >> 2, c4 = (i & 3) * 4;
        uint32_t shl = (uint32_t)(rrow & 1) * 4u;
        int col = rrow >> 1;
        float4 o;
        o.x = (float)((bt[c4 + 0][col] >> shl) & 1u);
        o.y = (float)((bt[c4 + 1][col] >> shl) & 1u);
        o.z = (float)((bt[c4 + 2][col] >> shl) & 1u);
        o.w = (float)((bt[c4 + 3][col] >> shl) & 1u);
        *(float4*)&out[(size_t)rrow * N_ + n0 + c4] = o;
    }
}

extern "C" void kernel_launch(void* const* d_in, const int* in_sizes, int n_in,
                              void* d_out, int out_size, void* d_ws, size_t ws_size,
                              hipStream_t stream) {
    const float* ext     = (const float*)d_in[0];
    const float* C       = (const float*)d_in[1];
    const float* memb    = (const float*)d_in[2];
    const float* thr     = (const float*)d_in[3];
    const float* refr_in = (const float*)d_in[4];

    char* ws = (char*)d_ws;
    uint32_t* bar    = (uint32_t*)(ws + OFF_BAR);
    unsigned char* sExp = (unsigned char*)(ws + OFF_SEXP);
    float*    out    = (float*)d_out;

    initbar_k<<<dim3(1), dim3(256), 0, stream>>>(bar);

    void* args[] = {(void*)&ext, (void*)&C, (void*)&memb, (void*)&thr,
                    (void*)&refr_in, (void*)&sExp, (void*)&out, (void*)&bar};
    hipLaunchCooperativeKernel((const void*)persist_k, dim3(NBLK), dim3(1024),
                               args, 0, stream);
}

// Round 22
// 126.806 us; speedup vs baseline: 1.0364x; 1.0364x over previous
//
#include <hip/hip_runtime.h>
#include <stdint.h>

#define N_ 4096
#define B_ 1024
#define ROWB 512        // nibble-packed spike row bytes (1024 batches x 4 bits)
#define NSTEPS_ 10
#define DEG_SLOTS 40    // padded neighbor-list slots (deg ~ Poisson(12); P(>40) ~ 1e-11)
#define PAD_E ((uint32_t)(N_ * ROWB)) // sentinel -> byte offset of zero pad row
#define NBLK 256
#define NCTR 16
#define FLAGI 512

// ws layout (bytes):
//   bar  : 0      .. 4224     u32[1056]: 16 ctrs at stride 32 + flag at [512]
//   deg  : 8192   .. 24576    u32[N]
//   nbr  : 24576  .. 679936   u32[N][DEG_SLOTS] entry = m*ROWB; sentinel N*ROWB
//   sExp : 679936 .. ~4.9MB   u4[2][(N+1)*ROWB] spike NIBBLES [n][b]; row N_ always zero
#define OFF_BAR  0
#define OFF_DEG  8192
#define OFF_NBR  24576
#define OFF_SEXP 679936
#define SEXP_BUF ((N_ + 1) * ROWB)

// build_k: neighbor lists from C (4096 blocks, full HBM BW). Block 0 zeros the
// barrier state; blocks 1,2 zero the sExp pad rows (consumed next dispatch).
__global__ __launch_bounds__(256) void build_k(const float* __restrict__ C,
                                               uint32_t* __restrict__ deg,
                                               uint32_t* __restrict__ nbr,
                                               uint32_t* __restrict__ bar,
                                               uint32_t* __restrict__ pad0,
                                               uint32_t* __restrict__ pad1) {
    __shared__ uint32_t cnt;
    int tid = threadIdx.x;
    int n = blockIdx.x;
    if (n == 0) { for (int i = tid; i < 1056; i += 256) bar[i] = 0u; }
    else if (n == 1) { if (tid < 128) pad0[tid] = 0u; }
    else if (n == 2) { if (tid < 128) pad1[tid] = 0u; }
    if (tid == 0) cnt = 0;
    __syncthreads();
    const float4* row = (const float4*)(C + (size_t)n * N_);
    for (int j4 = tid; j4 < N_ / 4; j4 += 256) {
        float4 v = row[j4];
        int base = j4 * 4;
        #pragma unroll
        for (int q = 0; q < 4; ++q) {
            float f = (q == 0) ? v.x : (q == 1) ? v.y : (q == 2) ? v.z : v.w;
            if (f != 0.0f) {
                uint32_t p = atomicAdd(&cnt, 1u);
                uint32_t m = (uint32_t)(base + q);
                if (p < DEG_SLOTS) nbr[n * DEG_SLOTS + p] = m * (uint32_t)ROWB;
            }
        }
    }
    __syncthreads();
    uint32_t c = min(cnt, (uint32_t)DEG_SLOTS);
    if (tid == 0) deg[n] = c;
    if (tid < DEG_SLOTS && (uint32_t)tid >= c)
        nbr[n * DEG_SLOTS + tid] = PAD_E;
}

// Two-hop grid barrier (round-16/20 champion scheme, verbatim): RELAXED
// L3-homed atomics for arrivals + flag; exactly ONE acquire load (buffer_inv)
// per block per phase, after the flag is seen.
__device__ __forceinline__ void gbar(uint32_t* bar, uint32_t phase) {
    __syncthreads();                         // all waves' spike stores acked
    int tid = threadIdx.x, bid = blockIdx.x;
    if (tid == 0)
        __hip_atomic_fetch_add(&bar[(bid & (NCTR - 1)) * 32], 1u,
                               __ATOMIC_RELAXED, __HIP_MEMORY_SCOPE_AGENT);
    if (bid == 0) {
        if (tid < NCTR) {
            uint32_t tgt = (NBLK / NCTR) * phase;
            while (__hip_atomic_load(&bar[tid * 32], __ATOMIC_RELAXED,
                                     __HIP_MEMORY_SCOPE_AGENT) < tgt)
                __builtin_amdgcn_s_sleep(2);
        }
        __syncthreads();
        if (tid == 0)
            __hip_atomic_store(&bar[FLAGI], phase,
                               __ATOMIC_RELAXED, __HIP_MEMORY_SCOPE_AGENT);
    }
    if (tid == 0) {
        while (__hip_atomic_load(&bar[FLAGI], __ATOMIC_RELAXED,
                                 __HIP_MEMORY_SCOPE_AGENT) < phase)
            __builtin_amdgcn_s_sleep(2);
        (void)__hip_atomic_load(&bar[FLAGI], __ATOMIC_ACQUIRE,  // one buffer_inv
                                __HIP_MEMORY_SCOPE_AGENT);
    }
    __syncthreads();
}

// Persistent kernel (round-20 structure + round-21 byte-packed extraction):
// block = 16 neurons x ALL 1024 batches (1024 threads, 16 waves); grid 256 =
// 1 block/CU. Wave = 1 neuron; refractory wave-local (one __ballot/step).
// Thread = 1 neuron x 16 batches; v in 16 VGPRs all 10 steps. Gather: one
// uint2 wave-inst reads a full 512 B nibble row; accumulate nibble-packed in
// chunks of <=15 neighbors; extraction via even/odd nibble split ->
// byte-packed sums -> cvt_f32_ubyte. Spike nibbles via one relaxed
// agent-scope b64 atomic store (L3 write-through); gathers PLAIN loads
// freshened by the barrier's inv.
__global__ __launch_bounds__(1024, 4) void persist_k(const float* __restrict__ ext,
                                                     const float* __restrict__ memb,
                                                     const float* __restrict__ thr,
                                                     const float* __restrict__ refr_in,
                                                     const uint32_t* __restrict__ deg,
                                                     const uint32_t* __restrict__ nbr,
                                                     unsigned char* __restrict__ sExp,
                                                     float* __restrict__ out,
                                                     uint32_t* bar) {
    __shared__ uint32_t s_nbr[16 * DEG_SLOTS];
    __shared__ unsigned char bt[16][528];    // output nibble tile (512 B rows + pad)

    int bid = blockIdx.x;
    int n0 = bid * 16;
    int tid = threadIdx.x;
    int wv = tid >> 6, lane = tid & 63;      // wave wv <-> neuron n0+wv
    int n = n0 + wv;
    int bbatch = lane * 16;                  // first of this thread's 16 batches
    int bbn = lane * 8;                      // nibble byte offset within row

    if (tid < 16 * DEG_SLOTS) s_nbr[tid] = nbr[(size_t)n0 * DEG_SLOTS + tid];
    __syncthreads();

    float tn = thr[n];                       // wave-uniform
    float r  = refr_in[n];                   // wave-local refractory state
    uint32_t dg = __builtin_amdgcn_readfirstlane(deg[n]);
    const uint32_t* lst = &s_nbr[wv * DEG_SLOTS];

    float v[16];
    {
        float mb = memb[n];
        #pragma unroll
        for (int i = 0; i < 16; ++i)         // column loads; lines shared across waves
            v[i] = __fadd_rn(mb, ext[(size_t)(bbatch + i) * N_ + n]);
    }

    uint32_t nib0 = 0, nib1 = 0;             // current step's spikes, nibble-packed

    // ---- step 0: external input only ----
    {
        uint32_t nb = (r != 0.0f) ? 0u : 1u;
        #pragma unroll
        for (int i = 0; i < 16; ++i) {
            int sp = (v[i] > tn) && nb;
            if (i < 8) nib0 |= (uint32_t)sp << (4 * i);
            else       nib1 |= (uint32_t)sp << (4 * (i - 8));
            v[i] = __fmul_rn(sp ? 0.0f : v[i], 0.95f);
        }
        unsigned long long p0 = (unsigned long long)nib0 | ((unsigned long long)nib1 << 32);
        __hip_atomic_store((unsigned long long*)(sExp + (size_t)n * ROWB + bbn), p0,
                           __ATOMIC_RELAXED, __HIP_MEMORY_SCOPE_AGENT);
        int any = (__ballot((nib0 | nib1) != 0) != 0ull);  // any over ALL batches
        r = any ? 3.0f : r;
        r = fminf(fmaxf(__fadd_rn(r, -1.0f), 0.0f), 10.0f);
    }
    gbar(bar, 1);

    // ---- steps 1..9 ----
    unsigned char* sprev = sExp;
    unsigned char* snext = sExp + (size_t)SEXP_BUF;
    for (int s = 1; s < NSTEPS_; ++s) {
        uint32_t nb = (r != 0.0f) ? 0u : 1u;
        uint2 accA = make_uint2(0u, 0u), accB = make_uint2(0u, 0u);
        uint2 accC = make_uint2(0u, 0u), accD = make_uint2(0u, 0u);
        #pragma unroll
        for (int j = 0; j < 8; ++j) {        // chunk A: slots 0..7 (max nibble 8)
            uint32_t e = lst[j];
            uint2 d2 = *(const uint2*)(sprev + e + bbn);
            accA.x += d2.x; accA.y += d2.y;
        }
        #pragma unroll
        for (int j = 8; j < 16; ++j) {       // chunk B: slots 8..15
            uint32_t e = lst[j];
            uint2 d2 = *(const uint2*)(sprev + e + bbn);
            accB.x += d2.x; accB.y += d2.y;
        }
        if (dg > 16) {                       // chunk C: slots 16..30 (15, wave-uniform rare)
            #pragma unroll
            for (int j = 16; j < 31; ++j) {
                uint32_t e = lst[j];
                uint2 d2 = *(const uint2*)(sprev + e + bbn);
                accC.x += d2.x; accC.y += d2.y;
            }
        }
        if (dg > 31) {                       // chunk D: slots 31..39 (9)
            #pragma unroll
            for (int j = 31; j < 40; ++j) {
                uint32_t e = lst[j];
                uint2 d2 = *(const uint2*)(sprev + e + bbn);
                accD.x += d2.x; accD.y += d2.y;
            }
        }
        uint32_t newn0 = 0, newn1 = 0;
        #pragma unroll
        for (int h = 0; h < 2; ++h) {        // dword half: batches 8h..8h+7
            uint32_t a = h ? accA.y : accA.x;
            uint32_t b = h ? accB.y : accB.x;
            uint32_t c = h ? accC.y : accC.x;
            uint32_t d = h ? accD.y : accD.x;
            // even/odd nibble split -> byte-packed sums (each byte <= 40)
            uint32_t sumE = (a & 0x0F0F0F0Fu) + (b & 0x0F0F0F0Fu) +
                            (c & 0x0F0F0F0Fu) + (d & 0x0F0F0F0Fu);   // batches h*8+{0,2,4,6}
            uint32_t sumO = ((a >> 4) & 0x0F0F0F0Fu) + ((b >> 4) & 0x0F0F0F0Fu) +
                            ((c >> 4) & 0x0F0F0F0Fu) + ((d >> 4) & 0x0F0F0F0Fu); // {1,3,5,7}
            uint32_t nh = 0;
            #pragma unroll
            for (int k = 0; k < 4; ++k) {
                float ce = (float)((sumE >> (8 * k)) & 255u);   // cvt_f32_ubyte idiom
                float co = (float)((sumO >> (8 * k)) & 255u);
                int be = h * 8 + 2 * k, bo = be + 1;
                float ve = __fadd_rn(v[be], __fmul_rn(0.1f, ce));
                float vo = __fadd_rn(v[bo], __fmul_rn(0.1f, co));
                int se = (ve > tn) && nb;
                int so = (vo > tn) && nb;
                nh |= (uint32_t)se << (4 * (2 * k));
                nh |= (uint32_t)so << (4 * (2 * k + 1));
                if (s < NSTEPS_ - 1) {
                    v[be] = __fmul_rn(se ? 0.0f : ve, 0.95f);
                    v[bo] = __fmul_rn(so ? 0.0f : vo, 0.95f);
                }
            }
            if (h == 0) newn0 = nh; else newn1 = nh;
        }
        nib0 = newn0; nib1 = newn1;
        if (s < NSTEPS_ - 1) {
            unsigned long long p0 = (unsigned long long)nib0 | ((unsigned long long)nib1 << 32);
            __hip_atomic_store((unsigned long long*)(snext + (size_t)n * ROWB + bbn), p0,
                               __ATOMIC_RELAXED, __HIP_MEMORY_SCOPE_AGENT);
            int any = (__ballot((nib0 | nib1) != 0) != 0ull);
            r = any ? 3.0f : r;
            r = fminf(fmaxf(__fadd_rn(r, -1.0f), 0.0f), 10.0f);
            gbar(bar, (uint32_t)s + 1);
        }
        unsigned char* t = sprev; sprev = snext; snext = t;
    }

    // ---- output: step-9 spike nibbles (in regs) -> tile -> [b][n] float4 ----
    *(uint2*)&bt[wv][bbn] = make_uint2(nib0, nib1);
    __syncthreads();
    #pragma unroll
    for (int p = 0; p < 4; ++p) {
        int i = tid + p * 1024;              // 4096 float4s: 1024 rows x 4 cols
        int rrow = i >> 2, c4 = (i & 3) * 4;
        uint32_t shl = (uint32_t)(rrow & 1) * 4u;
        int col = rrow >> 1;
        float4 o;
        o.x = (float)((bt[c4 + 0][col] >> shl) & 1u);
        o.y = (float)((bt[c4 + 1][col] >> shl) & 1u);
        o.z = (float)((bt[c4 + 2][col] >> shl) & 1u);
        o.w = (float)((bt[c4 + 3][col] >> shl) & 1u);
        *(float4*)&out[(size_t)rrow * N_ + n0 + c4] = o;
    }
}

extern "C" void kernel_launch(void* const* d_in, const int* in_sizes, int n_in,
                              void* d_out, int out_size, void* d_ws, size_t ws_size,
                              hipStream_t stream) {
    const float* ext     = (const float*)d_in[0];
    const float* C       = (const float*)d_in[1];
    const float* memb    = (const float*)d_in[2];
    const float* thr     = (const float*)d_in[3];
    const float* refr_in = (const float*)d_in[4];

    char* ws = (char*)d_ws;
    uint32_t* bar    = (uint32_t*)(ws + OFF_BAR);
    uint32_t* deg    = (uint32_t*)(ws + OFF_DEG);
    uint32_t* nbr    = (uint32_t*)(ws + OFF_NBR);
    unsigned char* sExp = (unsigned char*)(ws + OFF_SEXP);
    float*    out    = (float*)d_out;

    build_k<<<dim3(N_), dim3(256), 0, stream>>>(
        C, deg, nbr, bar,
        (uint32_t*)(sExp + (size_t)N_ * ROWB),
        (uint32_t*)(sExp + (size_t)SEXP_BUF + (size_t)N_ * ROWB));

    void* args[] = {(void*)&ext, (void*)&memb, (void*)&thr, (void*)&refr_in,
                    (void*)&deg, (void*)&nbr, (void*)&sExp, (void*)&out,
                    (void*)&bar};
    hipLaunchCooperativeKernel((const void*)persist_k, dim3(NBLK), dim3(1024),
                               args, 0, stream);
}